// Round 2
// baseline (2824.234 us; speedup 1.0000x reference)
//
#include <hip/hip_runtime.h>
#include <math.h>

// Problem constants (from reference): B=128, O=32, I=2048, Do=16, Di=8
#define B_N 128
#define O_N 32
#define I_N 2048
#define DO_N 16
#define DI_N 8

constexpr long BOI = (long)B_N * O_N * I_N;          // 8388608
constexpr long OUT_ELEMS = (long)B_N * O_N * DO_N;   // 65536
constexpr long COUPS_OFF = OUT_ELEMS;                // coups[3,B,O,I] after out
constexpr long BETAS_OFF = OUT_ELEMS + 3 * BOI;      // betas[3,B,O,I] after coups

// pass-kernel geometry: each thread = one (b, o); half-wave = 32 o's of one b
#define WAVES 8
#define THREADS (WAVES * 64)            // 512
#define B_PER_BLOCK (WAVES * 2)         // 16 b's per block (2 half-waves/wave)
#define BGROUPS (B_N / B_PER_BLOCK)     // 8
#define ICHUNK 16
#define IBLOCKS (I_N / ICHUNK)          // 128

// ---------------------------------------------------------------------------
// K0: fill constant outputs (coups[0]=1/32, betas[0]=0) and zero ws buffers
// ---------------------------------------------------------------------------
__global__ void fill_kernel(float* __restrict__ out, float* __restrict__ ws) {
    const float4 vc = make_float4(0.03125f, 0.03125f, 0.03125f, 0.03125f);
    const float4 vz = make_float4(0.f, 0.f, 0.f, 0.f);
    long tid = (long)blockIdx.x * blockDim.x + threadIdx.x;
    long stride = (long)gridDim.x * blockDim.x;
    float4* c0 = (float4*)(out + COUPS_OFF);  // coups[0]
    float4* b0 = (float4*)(out + BETAS_OFF);  // betas[0]
    float4* w4 = (float4*)ws;                 // sacc0,sacc1,sacc2,ocsum
    const long n = BOI / 4;                   // float4 count per region
    for (long idx = tid; idx < n; idx += stride) { c0[idx] = vc; b0[idx] = vz; }
    const long nw = OUT_ELEMS;                // 4 regions * OUT_ELEMS/4 float4
    for (long idx = tid; idx < nw; idx += stride) w4[idx] = vz;
}

// ---------------------------------------------------------------------------
// Pass kernel: recomputes uhat on the fly; c/bv buffered in registers and
// written as coalesced float4 bursts (one contiguous 64B run per thread).
// PASS==0: sacc += (1/32) * uhat  (coups[0]/betas[0] done by fill_kernel)
// PASS>=1: bv = dot(ocsum, uhat); c = softmax_o(bv); write betas/coups[PASS];
//          sacc += c * uhat
// ---------------------------------------------------------------------------
template<int PASS>
__global__ __launch_bounds__(THREADS)
void pass_kernel(const float* __restrict__ incaps,
                 const float* __restrict__ weight,
                 const float* __restrict__ ocsum,
                 float* __restrict__ sacc,
                 float* __restrict__ dout)
{
    const int lane = threadIdx.x & 63;
    const int wv   = threadIdx.x >> 6;
    const int o    = lane & 31;
    const int bh   = lane >> 5;
    const int ib   = blockIdx.x;                       // [0, IBLOCKS)
    const int bg   = blockIdx.y;                       // [0, BGROUPS)
    const int b    = bg * B_PER_BLOCK + wv * 2 + bh;
    const int i0   = ib * ICHUNK;

    // cumulative outcaps sum for this (b,o) — fixed for whole kernel
    float oc[DO_N];
    if (PASS > 0) {
        const float4* p = (const float4*)(ocsum + ((long)b * O_N + o) * DO_N);
#pragma unroll
        for (int q = 0; q < 4; ++q) {
            float4 v = p[q];
            oc[4*q+0] = v.x; oc[4*q+1] = v.y; oc[4*q+2] = v.z; oc[4*q+3] = v.w;
        }
    }

    float sa[DO_N];
#pragma unroll
    for (int d = 0; d < DO_N; ++d) sa[d] = 0.f;

    float cbuf[ICHUNK];
    float bbuf[ICHUNK];

    for (int ii = 0; ii < ICHUNK; ++ii) {
        const int i = i0 + ii;

        // incaps[b, i, 0..7] — same 32B for all lanes of a half-wave (bcast)
        float x[DI_N];
        {
            const float4* p = (const float4*)(incaps + ((long)b * I_N + i) * DI_N);
            float4 a = p[0], bq = p[1];
            x[0]=a.x; x[1]=a.y; x[2]=a.z; x[3]=a.w;
            x[4]=bq.x; x[5]=bq.y; x[6]=bq.z; x[7]=bq.w;
        }

        // uhat[b,o,i,d] = sum_k weight[o,i,d,k] * incaps[b,i,k]
        float uh[DO_N];
        const float4* wp = (const float4*)(weight + ((long)o * I_N + i) * (DO_N * DI_N));
#pragma unroll
        for (int d = 0; d < DO_N; ++d) {
            float4 wa = wp[2*d], wb = wp[2*d+1];
            uh[d] = wa.x*x[0] + wa.y*x[1] + wa.z*x[2] + wa.w*x[3]
                  + wb.x*x[4] + wb.y*x[5] + wb.z*x[6] + wb.w*x[7];
        }

        if (PASS == 0) {
#pragma unroll
            for (int d = 0; d < DO_N; ++d) sa[d] += uh[d];
        } else {
            float bv = 0.f;
#pragma unroll
            for (int d = 0; d < DO_N; ++d) bv += oc[d] * uh[d];

            // softmax over o (axis=1) within the 32-lane half-wave
            float m = bv;
#pragma unroll
            for (int msk = 16; msk >= 1; msk >>= 1)
                m = fmaxf(m, __shfl_xor(m, msk));
            float e = expf(bv - m);
            float s = e;
#pragma unroll
            for (int msk = 16; msk >= 1; msk >>= 1)
                s += __shfl_xor(s, msk);
            float c = e / s;

            cbuf[ii] = c;
            bbuf[ii] = bv;

#pragma unroll
            for (int d = 0; d < DO_N; ++d) sa[d] += c * uh[d];
        }
    }

    if (PASS > 0) {
        // coalesced burst: this thread owns 64 contiguous bytes per region
        const long rbase = ((long)b * O_N + o) * I_N + i0;
        float4* cp = (float4*)(dout + COUPS_OFF + (long)PASS * BOI + rbase);
        float4* bp = (float4*)(dout + BETAS_OFF + (long)PASS * BOI + rbase);
#pragma unroll
        for (int q = 0; q < ICHUNK / 4; ++q) {
            cp[q] = make_float4(cbuf[4*q+0], cbuf[4*q+1], cbuf[4*q+2], cbuf[4*q+3]);
            bp[q] = make_float4(bbuf[4*q+0], bbuf[4*q+1], bbuf[4*q+2], bbuf[4*q+3]);
        }
    }

    const float scale = (PASS == 0) ? (1.0f / 32.0f) : 1.0f;
#pragma unroll
    for (int d = 0; d < DO_N; ++d)
        atomicAdd(&sacc[((long)b * O_N + o) * DO_N + d], sa[d] * scale);
}

// ---------------------------------------------------------------------------
// Squash: outcaps = squash(sacc); accumulate into ocsum (mid passes) or
// write final out (last pass).
// ---------------------------------------------------------------------------
template<bool FINAL>
__global__ void squash_kernel(const float* __restrict__ sacc,
                              float* __restrict__ ocsum,
                              float* __restrict__ dout)
{
    int t = blockIdx.x * blockDim.x + threadIdx.x;   // (b*O + o)
    if (t >= B_N * O_N) return;
    float v[DO_N]; float n2 = 0.f;
    const float4* p = (const float4*)(sacc + (long)t * DO_N);
#pragma unroll
    for (int q = 0; q < 4; ++q) {
        float4 a = p[q];
        v[4*q+0]=a.x; v[4*q+1]=a.y; v[4*q+2]=a.z; v[4*q+3]=a.w;
    }
#pragma unroll
    for (int d = 0; d < DO_N; ++d) n2 += v[d]*v[d];
    float n = sqrtf(n2);
    float scale = n2 / ((1.f + n2) * (n + 1e-8f));
    if (FINAL) {
#pragma unroll
        for (int d = 0; d < DO_N; ++d) dout[(long)t * DO_N + d] = scale * v[d];
    } else {
#pragma unroll
        for (int d = 0; d < DO_N; ++d) ocsum[(long)t * DO_N + d] += scale * v[d];
    }
}

// ---------------------------------------------------------------------------
extern "C" void kernel_launch(void* const* d_in, const int* in_sizes, int n_in,
                              void* d_out, int out_size, void* d_ws, size_t ws_size,
                              hipStream_t stream)
{
    const float* incaps = (const float*)d_in[0];   // [B, I, Di] f32
    const float* weight = (const float*)d_in[1];   // [O, I, Do, Di] f32
    float* out = (float*)d_out;
    float* ws  = (float*)d_ws;

    float* sacc0 = ws;                    // [B,O,16]
    float* sacc1 = ws + OUT_ELEMS;
    float* sacc2 = ws + 2 * OUT_ELEMS;
    float* ocsum = ws + 3 * OUT_ELEMS;    // cumulative outcaps

    fill_kernel<<<2048, 256, 0, stream>>>(out, ws);

    dim3 pg(IBLOCKS, BGROUPS);
    pass_kernel<0><<<pg, THREADS, 0, stream>>>(incaps, weight, ocsum, sacc0, out);
    squash_kernel<false><<<(B_N * O_N + 255) / 256, 256, 0, stream>>>(sacc0, ocsum, nullptr);
    pass_kernel<1><<<pg, THREADS, 0, stream>>>(incaps, weight, ocsum, sacc1, out);
    squash_kernel<false><<<(B_N * O_N + 255) / 256, 256, 0, stream>>>(sacc1, ocsum, nullptr);
    pass_kernel<2><<<pg, THREADS, 0, stream>>>(incaps, weight, ocsum, sacc2, out);
    squash_kernel<true><<<(B_N * O_N + 255) / 256, 256, 0, stream>>>(sacc2, ocsum, out);
}

// Round 3
// 2127.634 us; speedup vs baseline: 1.3274x; 1.3274x over previous
//
#include <hip/hip_runtime.h>
#include <math.h>

// Problem constants (from reference): B=128, O=32, I=2048, Do=16, Di=8
#define B_N 128
#define O_N 32
#define I_N 2048
#define DO_N 16
#define DI_N 8

constexpr long BOI = (long)B_N * O_N * I_N;          // 8388608
constexpr long OUT_ELEMS = (long)B_N * O_N * DO_N;   // 65536
constexpr long COUPS_OFF = OUT_ELEMS;                // coups[3,B,O,I] after out
constexpr long BETAS_OFF = OUT_ELEMS + 3 * BOI;      // betas[3,B,O,I] after coups

// pass-kernel geometry: thread=(b,o); half-wave = 32 o's of one b
#define WAVES 4
#define THREADS (WAVES * 64)            // 256
#define B_PER_BLOCK (WAVES * 2)         // 8 b's per block
#define BGROUPS (B_N / B_PER_BLOCK)     // 16
#define ICHUNK 32                       // one full 128B line per (b,o) row
#define IBLOCKS (I_N / ICHUNK)          // 64
#define TPAD 33                         // padded i-dim (bank-conflict-free)

// dynamic LDS: [wave][buf(c=0,bv=1)][bh][o][TPAD] floats
__device__ __forceinline__ int lds_base(int wv, int buf, int bh) {
    return ((wv * 2 + buf) * 2 + bh) * (O_N * TPAD);
}

// ---------------------------------------------------------------------------
// K0: fill constant outputs (coups[0]=1/32, betas[0]=0) and zero ws buffers
// ---------------------------------------------------------------------------
__global__ void fill_kernel(float* __restrict__ out, float* __restrict__ ws) {
    const float4 vc = make_float4(0.03125f, 0.03125f, 0.03125f, 0.03125f);
    const float4 vz = make_float4(0.f, 0.f, 0.f, 0.f);
    long tid = (long)blockIdx.x * blockDim.x + threadIdx.x;
    long stride = (long)gridDim.x * blockDim.x;
    float4* c0 = (float4*)(out + COUPS_OFF);  // coups[0]
    float4* b0 = (float4*)(out + BETAS_OFF);  // betas[0]
    float4* w4 = (float4*)ws;                 // sacc0,sacc1,sacc2,ocsum
    const long n = BOI / 4;
    for (long idx = tid; idx < n; idx += stride) { c0[idx] = vc; b0[idx] = vz; }
    const long nw = OUT_ELEMS;                // 4 regions * (OUT_ELEMS/4) f4
    for (long idx = tid; idx < nw; idx += stride) w4[idx] = vz;
}

// ---------------------------------------------------------------------------
// Pass kernel: recomputes uhat on the fly. c/bv go straight to a per-wave
// LDS tile (no register arrays -> no scratch), then are flushed as full
// 128B-line coalesced stores.
// PASS==0: sacc += (1/32)*uhat  (coups[0]/betas[0] done by fill_kernel)
// PASS>=1: bv = dot(ocsum, uhat); c = softmax_o(bv); write betas/coups[PASS]
// ---------------------------------------------------------------------------
template<int PASS>
__global__ __launch_bounds__(THREADS)
void pass_kernel(const float* __restrict__ incaps,
                 const float* __restrict__ weight,
                 const float* __restrict__ ocsum,
                 float* __restrict__ sacc,
                 float* __restrict__ dout)
{
    extern __shared__ float tl[];

    const int lane = threadIdx.x & 63;
    const int wv   = threadIdx.x >> 6;
    const int o    = lane & 31;
    const int bh   = lane >> 5;
    const int ib   = blockIdx.x;                       // [0, IBLOCKS)
    const int bg   = blockIdx.y;                       // [0, BGROUPS)
    const int b    = bg * B_PER_BLOCK + wv * 2 + bh;
    const int i0   = ib * ICHUNK;

    // cumulative outcaps sum for this (b,o) — fixed for the whole kernel
    float oc[DO_N];
    if (PASS > 0) {
        const float4* p = (const float4*)(ocsum + ((long)b * O_N + o) * DO_N);
#pragma unroll
        for (int q = 0; q < 4; ++q) {
            float4 v = p[q];
            oc[4*q+0] = v.x; oc[4*q+1] = v.y; oc[4*q+2] = v.z; oc[4*q+3] = v.w;
        }
    }

    float sa[DO_N];
#pragma unroll
    for (int d = 0; d < DO_N; ++d) sa[d] = 0.f;

    const float* wrow = weight + ((long)o * I_N + i0) * (DO_N * DI_N);
    const float* xrow = incaps + ((long)b * I_N + i0) * DI_N;
    const int cbase = lds_base(wv, 0, bh) + o * TPAD;   // c tile row
    const int vbase = lds_base(wv, 1, bh) + o * TPAD;   // bv tile row

#pragma unroll 4
    for (int ii = 0; ii < ICHUNK; ++ii) {
        // incaps[b, i0+ii, 0..7] — 32B broadcast across the half-wave
        float x[DI_N];
        {
            const float4* p = (const float4*)(xrow + ii * DI_N);
            float4 a = p[0], bq = p[1];
            x[0]=a.x; x[1]=a.y; x[2]=a.z; x[3]=a.w;
            x[4]=bq.x; x[5]=bq.y; x[6]=bq.z; x[7]=bq.w;
        }

        // uhat[b,o,i,d] = sum_k weight[o,i,d,k] * incaps[b,i,k]
        float uh[DO_N];
        const float4* wp = (const float4*)(wrow + ii * (DO_N * DI_N));
#pragma unroll
        for (int d = 0; d < DO_N; ++d) {
            float4 wa = wp[2*d], wb = wp[2*d+1];
            uh[d] = wa.x*x[0] + wa.y*x[1] + wa.z*x[2] + wa.w*x[3]
                  + wb.x*x[4] + wb.y*x[5] + wb.z*x[6] + wb.w*x[7];
        }

        if (PASS == 0) {
#pragma unroll
            for (int d = 0; d < DO_N; ++d) sa[d] += uh[d];
        } else {
            float bv = 0.f;
#pragma unroll
            for (int d = 0; d < DO_N; ++d) bv += oc[d] * uh[d];

            // softmax over o (axis=1) within the 32-lane half-wave
            float m = bv;
#pragma unroll
            for (int msk = 16; msk >= 1; msk >>= 1)
                m = fmaxf(m, __shfl_xor(m, msk));
            float e = expf(bv - m);
            float s = e;
#pragma unroll
            for (int msk = 16; msk >= 1; msk >>= 1)
                s += __shfl_xor(s, msk);
            float c = e / s;

            // straight to LDS (no register arrays -> no scratch)
            tl[cbase + ii] = c;
            tl[vbase + ii] = bv;

#pragma unroll
            for (int d = 0; d < DO_N; ++d) sa[d] += c * uh[d];
        }
    }

    if (PASS > 0) {
        // flush: per store instruction, 64 lanes cover two complete,
        // fully-dirty 128B cache lines (one o-row per 32-lane half)
        const int col  = lane & 31;
        const int half = lane >> 5;
        const int bfl  = bg * B_PER_BLOCK + wv * 2 + half;
        const long gbase = (long)bfl * O_N * I_N + i0 + col;
        float* cp = dout + COUPS_OFF + (long)PASS * BOI + gbase;
        float* bp = dout + BETAS_OFF + (long)PASS * BOI + gbase;
        const float* tc = &tl[lds_base(wv, 0, half)];
        const float* tb = &tl[lds_base(wv, 1, half)];
#pragma unroll
        for (int r = 0; r < O_N; ++r) {
            cp[(long)r * I_N] = tc[r * TPAD + col];
            bp[(long)r * I_N] = tb[r * TPAD + col];
        }
    }

    const float scale = (PASS == 0) ? (1.0f / 32.0f) : 1.0f;
#pragma unroll
    for (int d = 0; d < DO_N; ++d)
        atomicAdd(&sacc[((long)b * O_N + o) * DO_N + d], sa[d] * scale);
}

// ---------------------------------------------------------------------------
// Squash: outcaps = squash(sacc); accumulate into ocsum (mid passes) or
// write final out (last pass).
// ---------------------------------------------------------------------------
template<bool FINAL>
__global__ void squash_kernel(const float* __restrict__ sacc,
                              float* __restrict__ ocsum,
                              float* __restrict__ dout)
{
    int t = blockIdx.x * blockDim.x + threadIdx.x;   // (b*O + o)
    if (t >= B_N * O_N) return;
    float v[DO_N]; float n2 = 0.f;
    const float4* p = (const float4*)(sacc + (long)t * DO_N);
#pragma unroll
    for (int q = 0; q < 4; ++q) {
        float4 a = p[q];
        v[4*q+0]=a.x; v[4*q+1]=a.y; v[4*q+2]=a.z; v[4*q+3]=a.w;
    }
#pragma unroll
    for (int d = 0; d < DO_N; ++d) n2 += v[d]*v[d];
    float n = sqrtf(n2);
    float scale = n2 / ((1.f + n2) * (n + 1e-8f));
    if (FINAL) {
#pragma unroll
        for (int d = 0; d < DO_N; ++d) dout[(long)t * DO_N + d] = scale * v[d];
    } else {
#pragma unroll
        for (int d = 0; d < DO_N; ++d) ocsum[(long)t * DO_N + d] += scale * v[d];
    }
}

// ---------------------------------------------------------------------------
extern "C" void kernel_launch(void* const* d_in, const int* in_sizes, int n_in,
                              void* d_out, int out_size, void* d_ws, size_t ws_size,
                              hipStream_t stream)
{
    const float* incaps = (const float*)d_in[0];   // [B, I, Di] f32
    const float* weight = (const float*)d_in[1];   // [O, I, Do, Di] f32
    float* out = (float*)d_out;
    float* ws  = (float*)d_ws;

    float* sacc0 = ws;                    // [B,O,16]
    float* sacc1 = ws + OUT_ELEMS;
    float* sacc2 = ws + 2 * OUT_ELEMS;
    float* ocsum = ws + 3 * OUT_ELEMS;    // cumulative outcaps

    fill_kernel<<<2048, 256, 0, stream>>>(out, ws);

    const size_t tile_bytes = (size_t)WAVES * 2 * 2 * O_N * TPAD * sizeof(float);

    dim3 pg(IBLOCKS, BGROUPS);
    pass_kernel<0><<<pg, THREADS, 0, stream>>>(incaps, weight, ocsum, sacc0, out);
    squash_kernel<false><<<(B_N * O_N + 255) / 256, 256, 0, stream>>>(sacc0, ocsum, nullptr);
    pass_kernel<1><<<pg, THREADS, tile_bytes, stream>>>(incaps, weight, ocsum, sacc1, out);
    squash_kernel<false><<<(B_N * O_N + 255) / 256, 256, 0, stream>>>(sacc1, ocsum, nullptr);
    pass_kernel<2><<<pg, THREADS, tile_bytes, stream>>>(incaps, weight, ocsum, sacc2, out);
    squash_kernel<true><<<(B_N * O_N + 255) / 256, 256, 0, stream>>>(sacc2, ocsum, out);
}

// Round 5
// 1115.483 us; speedup vs baseline: 2.5318x; 1.9074x over previous
//
#include <hip/hip_runtime.h>
#include <math.h>

// Problem constants (from reference): B=128, O=32, I=2048, Do=16, Di=8
#define B_N 128
#define O_N 32
#define I_N 2048
#define DO_N 16
#define DI_N 8

constexpr long BOI = (long)B_N * O_N * I_N;          // 8388608
constexpr long OUT_ELEMS = (long)B_N * O_N * DO_N;   // 65536
constexpr long COUPS_OFF = OUT_ELEMS;                // coups[3,B,O,I] after out
constexpr long BETAS_OFF = OUT_ELEMS + 3 * BOI;      // betas[3,B,O,I] after coups

// pass-kernel geometry:
//   256 threads = 8 half-waves; thread = (o = tid&31, g = tid>>5 in 0..7)
//   each thread computes 2 b's: b = bg*16 + 2g + {0,1}  -> NB=16 b per block
//   per stage: ONE i; weight rows [32 o][512B] staged to LDS via
//   global_load_lds with a 16B-granular XOR involution (conflict-free b128
//   reads; upper half-wave broadcasts).
#define THREADS 256
#define NB 16
#define BGROUPS (B_N / NB)              // 8
#define ICHUNK 32
#define IBLOCKS (I_N / ICHUNK)          // 64
#define IWIN 16                         // bv flush window (two flushes)

__device__ __forceinline__ void glds16(const float* gsrc, float* ldst) {
    __builtin_amdgcn_global_load_lds(
        (const __attribute__((address_space(1))) unsigned int*)gsrc,
        (__attribute__((address_space(3))) unsigned int*)ldst,
        16, 0, 0);
}

// ---------------------------------------------------------------------------
// K0: fill constant outputs (coups[0]=1/32, betas[0]=0) and zero ws buffers
// ---------------------------------------------------------------------------
__global__ void fill_kernel(float* __restrict__ out, float* __restrict__ ws) {
    const float4 vc = make_float4(0.03125f, 0.03125f, 0.03125f, 0.03125f);
    const float4 vz = make_float4(0.f, 0.f, 0.f, 0.f);
    long tid = (long)blockIdx.x * blockDim.x + threadIdx.x;
    long stride = (long)gridDim.x * blockDim.x;
    float4* c0 = (float4*)(out + COUPS_OFF);
    float4* b0 = (float4*)(out + BETAS_OFF);
    float4* w4 = (float4*)ws;                 // sacc0,sacc1,sacc2,ocsum
    const long n = BOI / 4;
    for (long idx = tid; idx < n; idx += stride) { c0[idx] = vc; b0[idx] = vz; }
    const long nw = OUT_ELEMS;                // 4 regions * (OUT_ELEMS/4) f4
    for (long idx = tid; idx < nw; idx += stride) w4[idx] = vz;
}

// ---------------------------------------------------------------------------
// Pass kernel.
// PASS==0: sacc += (1/32)*uhat      (coups[0]/betas[0] done by fill_kernel)
// PASS>=1: bv = dot(ocsum, uhat); c = softmax_o(bv); stage bv in a swizzled
//          LDS window; flush betas/coups[PASS] coalesced, recomputing the
//          softmax stats from the staged bv at flush time.
// ---------------------------------------------------------------------------
template<int PASS>
__global__ __launch_bounds__(THREADS, 2)
void pass_kernel(const float* __restrict__ incaps,
                 const float* __restrict__ weight,
                 const float* __restrict__ ocsum,
                 float* __restrict__ sacc,
                 float* __restrict__ dout)
{
    __shared__ float wtile[32 * 128];        // 16 KiB: [o][128f], swizzled
    __shared__ float bvt[NB][O_N][IWIN];     // 32 KiB: bank-swizzled columns

    const int tid = threadIdx.x;
    const int o   = tid & 31;
    const int g   = tid >> 5;                // 0..7
    const int ib  = blockIdx.x;              // i-chunk
    const int bg  = blockIdx.y;              // b-group of 16
    const int i0  = ib * ICHUNK;
    const int lb0 = 2 * g;
    const int lb1 = 2 * g + 1;
    const int b0  = bg * NB + lb0;
    const int b1  = b0 + 1;

    // ocsum for (b0,o,:) and (b1,o,:) — fixed for the whole kernel
    float oc0[DO_N], oc1[DO_N];
    if (PASS > 0) {
        const float4* p0 = (const float4*)(ocsum + ((long)b0 * O_N + o) * DO_N);
        const float4* p1 = (const float4*)(ocsum + ((long)b1 * O_N + o) * DO_N);
#pragma unroll
        for (int q = 0; q < 4; ++q) {
            float4 v0 = p0[q], v1 = p1[q];
            oc0[4*q+0]=v0.x; oc0[4*q+1]=v0.y; oc0[4*q+2]=v0.z; oc0[4*q+3]=v0.w;
            oc1[4*q+0]=v1.x; oc1[4*q+1]=v1.y; oc1[4*q+2]=v1.z; oc1[4*q+3]=v1.w;
        }
    }

    float sa0[DO_N], sa1[DO_N];
#pragma unroll
    for (int d = 0; d < DO_N; ++d) { sa0[d] = 0.f; sa1[d] = 0.f; }

    // ---- flush lambda: write betas/coups for one 16-i window ----
    auto flush = [&](int w) {
        const int iwf = tid & 15;            // i within window
        const int lbf = tid >> 4;            // 0..15 (local b)
        float m = -3.4e38f;
#pragma unroll 8
        for (int r = 0; r < O_N; ++r)
            m = fmaxf(m, bvt[lbf][r][iwf ^ ((r ^ lbf) & 15)]);
        float sden = 0.f;
#pragma unroll 8
        for (int r = 0; r < O_N; ++r)
            sden += expf(bvt[lbf][r][iwf ^ ((r ^ lbf) & 15)] - m);
        const float inv = 1.0f / sden;
        const int gb = bg * NB + lbf;
        const long gbase = (long)gb * O_N * I_N + (i0 + w * IWIN + iwf);
        float* cp = dout + COUPS_OFF + (long)PASS * BOI + gbase;
        float* bp = dout + BETAS_OFF + (long)PASS * BOI + gbase;
#pragma unroll 8
        for (int r = 0; r < O_N; ++r) {
            float bv = bvt[lbf][r][iwf ^ ((r ^ lbf) & 15)];
            cp[(long)r * I_N] = expf(bv - m) * inv;
            bp[(long)r * I_N] = bv;
        }
    };

    for (int s = 0; s < ICHUNK; ++s) {
        const int i = i0 + s;

        if (PASS > 0 && s == IWIN) {         // window 0 complete
            __syncthreads();                 // bvt writes visible
            flush(0);
        }
        __syncthreads();                     // WAR: wtile reads done (+flush)

        // stage weight [32 o][512B] for this i; 16B-granular involution
#pragma unroll
        for (int j = 0; j < 4; ++j) {
            const int L  = j * 4096 + tid * 16;   // byte offset in 16 KiB
            const int oo = L >> 9;                // weight row (o)
            const int rp = L & 511;               // byte within row
            const int r  = rp ^ ((oo & 7) << 4);  // involution, 16B units
            glds16(weight + ((long)oo * I_N + i) * 128 + (r >> 2),
                   wtile + (L >> 2));
        }

        // incaps[b, i, 0..7] — 32B broadcast within each half-wave
        float x0[DI_N], x1[DI_N];
        {
            const float4* p = (const float4*)(incaps + ((long)b0 * I_N + i) * DI_N);
            float4 a = p[0], bq = p[1];
            x0[0]=a.x; x0[1]=a.y; x0[2]=a.z; x0[3]=a.w;
            x0[4]=bq.x; x0[5]=bq.y; x0[6]=bq.z; x0[7]=bq.w;
            const float4* qp = (const float4*)(incaps + ((long)b1 * I_N + i) * DI_N);
            float4 c = qp[0], dq = qp[1];
            x1[0]=c.x; x1[1]=c.y; x1[2]=c.z; x1[3]=c.w;
            x1[4]=dq.x; x1[5]=dq.y; x1[6]=dq.z; x1[7]=dq.w;
        }

        __syncthreads();                     // staging complete (vmcnt drain)

        // conflict-free swizzled b128 reads; uh for both b's
        const char* wrow = (const char*)wtile + o * 512;
        const int swz = (o & 7) << 4;
        float uh0[DO_N], uh1[DO_N];
#pragma unroll
        for (int d = 0; d < DO_N; ++d) {
            float4 A = *(const float4*)(wrow + ((d * 32)      ^ swz));
            float4 Bq = *(const float4*)(wrow + ((d * 32 + 16) ^ swz));
            uh0[d] = A.x*x0[0] + A.y*x0[1] + A.z*x0[2] + A.w*x0[3]
                   + Bq.x*x0[4] + Bq.y*x0[5] + Bq.z*x0[6] + Bq.w*x0[7];
            uh1[d] = A.x*x1[0] + A.y*x1[1] + A.z*x1[2] + A.w*x1[3]
                   + Bq.x*x1[4] + Bq.y*x1[5] + Bq.z*x1[6] + Bq.w*x1[7];
        }

        if (PASS == 0) {
#pragma unroll
            for (int d = 0; d < DO_N; ++d) { sa0[d] += uh0[d]; sa1[d] += uh1[d]; }
        } else {
            float bv0 = 0.f, bv1 = 0.f;
#pragma unroll
            for (int d = 0; d < DO_N; ++d) { bv0 += oc0[d]*uh0[d]; bv1 += oc1[d]*uh1[d]; }

            // softmax over o within each 32-lane half-wave
            float m0 = bv0, m1 = bv1;
#pragma unroll
            for (int msk = 16; msk >= 1; msk >>= 1) {
                m0 = fmaxf(m0, __shfl_xor(m0, msk));
                m1 = fmaxf(m1, __shfl_xor(m1, msk));
            }
            float e0 = expf(bv0 - m0), e1 = expf(bv1 - m1);
            float s0 = e0, s1 = e1;
#pragma unroll
            for (int msk = 16; msk >= 1; msk >>= 1) {
                s0 += __shfl_xor(s0, msk);
                s1 += __shfl_xor(s1, msk);
            }
            float c0 = e0 / s0, c1 = e1 / s1;

            const int iw = s & (IWIN - 1);
            bvt[lb0][o][iw ^ ((o ^ lb0) & 15)] = bv0;
            bvt[lb1][o][iw ^ ((o ^ lb1) & 15)] = bv1;

#pragma unroll
            for (int d = 0; d < DO_N; ++d) { sa0[d] += c0*uh0[d]; sa1[d] += c1*uh1[d]; }
        }
    }

    if (PASS > 0) {
        __syncthreads();                     // window 1 bvt writes visible
        flush(1);
    }

    const float scale = (PASS == 0) ? (1.0f / 32.0f) : 1.0f;
#pragma unroll
    for (int d = 0; d < DO_N; ++d) {
        atomicAdd(&sacc[((long)b0 * O_N + o) * DO_N + d], sa0[d] * scale);
        atomicAdd(&sacc[((long)b1 * O_N + o) * DO_N + d], sa1[d] * scale);
    }
}

// ---------------------------------------------------------------------------
// Squash: outcaps = squash(sacc); accumulate into ocsum (mid passes) or
// write final out (last pass).
// ---------------------------------------------------------------------------
template<bool FINAL>
__global__ void squash_kernel(const float* __restrict__ sacc,
                              float* __restrict__ ocsum,
                              float* __restrict__ dout)
{
    int t = blockIdx.x * blockDim.x + threadIdx.x;   // (b*O + o)
    if (t >= B_N * O_N) return;
    float v[DO_N]; float n2 = 0.f;
    const float4* p = (const float4*)(sacc + (long)t * DO_N);
#pragma unroll
    for (int q = 0; q < 4; ++q) {
        float4 a = p[q];
        v[4*q+0]=a.x; v[4*q+1]=a.y; v[4*q+2]=a.z; v[4*q+3]=a.w;
    }
#pragma unroll
    for (int d = 0; d < DO_N; ++d) n2 += v[d]*v[d];
    float n = sqrtf(n2);
    float scale = n2 / ((1.f + n2) * (n + 1e-8f));
    if (FINAL) {
#pragma unroll
        for (int d = 0; d < DO_N; ++d) dout[(long)t * DO_N + d] = scale * v[d];
    } else {
#pragma unroll
        for (int d = 0; d < DO_N; ++d) ocsum[(long)t * DO_N + d] += scale * v[d];
    }
}

// ---------------------------------------------------------------------------
extern "C" void kernel_launch(void* const* d_in, const int* in_sizes, int n_in,
                              void* d_out, int out_size, void* d_ws, size_t ws_size,
                              hipStream_t stream)
{
    const float* incaps = (const float*)d_in[0];   // [B, I, Di] f32
    const float* weight = (const float*)d_in[1];   // [O, I, Do, Di] f32
    float* out = (float*)d_out;
    float* ws  = (float*)d_ws;

    float* sacc0 = ws;                    // [B,O,16]
    float* sacc1 = ws + OUT_ELEMS;
    float* sacc2 = ws + 2 * OUT_ELEMS;
    float* ocsum = ws + 3 * OUT_ELEMS;    // cumulative outcaps

    fill_kernel<<<2048, 256, 0, stream>>>(out, ws);

    dim3 pg(IBLOCKS, BGROUPS);            // (64, 8) = 512 blocks
    pass_kernel<0><<<pg, THREADS, 0, stream>>>(incaps, weight, ocsum, sacc0, out);
    squash_kernel<false><<<(B_N * O_N + 255) / 256, 256, 0, stream>>>(sacc0, ocsum, nullptr);
    pass_kernel<1><<<pg, THREADS, 0, stream>>>(incaps, weight, ocsum, sacc1, out);
    squash_kernel<false><<<(B_N * O_N + 255) / 256, 256, 0, stream>>>(sacc1, ocsum, nullptr);
    pass_kernel<2><<<pg, THREADS, 0, stream>>>(incaps, weight, ocsum, sacc2, out);
    squash_kernel<true><<<(B_N * O_N + 255) / 256, 256, 0, stream>>>(sacc2, ocsum, out);
}